// Round 1
// baseline (341.413 us; speedup 1.0000x reference)
//
#include <hip/hip_runtime.h>
#include <cstdint>
#include <cstddef>

// MaskEstimator: 24 independent 2-layer GLU MLPs.
//  x:(2048,24,512) f32, W0:(24,512,1024), b0:(24,1024), W1:(512,4032), b1:(4032)
//  h = glu(x@W0+b0) ; out[:, off/2 : off/2+di] = glu(h_band @ W1[:,off:off+2di] + b1[...])
// Strategy: cast everything to fp16 (threshold 1.33e-2 >> fp16 GEMM error ~1e-3),
// MFMA 16x16x32_f16, 128x128 tiles, BK=64, global_load_lds dwordx4 staging,
// XOR-swizzled LDS (conflict-free ds_read_b128), GLU pairs interleaved at cast
// time so epilogue pairing is a single __shfl_xor(1).

typedef _Float16 f16;
typedef _Float16 f16x8 __attribute__((ext_vector_type(8)));
typedef float floatx4 __attribute__((ext_vector_type(4)));

#define BT 2048   // B*T
#define NB 24

// band i: di = 8 << (i/4); off2 = 2*cumsum(di)
__device__ __forceinline__ int band_di(int b){ return 8 << (b >> 2); }
__device__ __forceinline__ int band_off2(int b){
  int g = b >> 2;
  return 2 * (32 * ((1 << g) - 1) + (b & 3) * (8 << g));
}

__device__ __forceinline__ float fsigm(float x){
  return __builtin_amdgcn_rcpf(1.f + __expf(-x));
}
__device__ __forceinline__ float ftanh(float x){
  // 1 - 2/(1+e^{2x}); saturates correctly for |x| large (rcp(inf)=0)
  return 1.f - 2.f * __builtin_amdgcn_rcpf(1.f + __expf(2.f * x));
}

__device__ __forceinline__ void gl_lds16(const void* g, void* l){
  __builtin_amdgcn_global_load_lds(
      (const __attribute__((address_space(1))) unsigned int*)g,
      (__attribute__((address_space(3))) unsigned int*)l, 16, 0, 0);
}

// ---------------- cast kernels ----------------

// x f32 -> f16, same layout (2048,24,512). 1 float4 per thread.
__global__ __launch_bounds__(256) void cast_x(const float4* __restrict__ in,
                                              f16* __restrict__ out){
  int t = blockIdx.x * 256 + threadIdx.x;   // 6291456 total
  float4 v = in[t];
  f16 o0 = (f16)v.x, o1 = (f16)v.y, o2 = (f16)v.z, o3 = (f16)v.w;
  typedef _Float16 f16x4 __attribute__((ext_vector_type(4)));
  f16x4 o = { o0, o1, o2, o3 };
  *(f16x4*)(out + (size_t)t * 4) = o;
}

// W0 (24,512,1024) -> w0t (24,1024,512) f16, columns interleaved:
// perm row p: orig col = (p&1) ? 512 + p/2 : p/2.
// grid: band(24) x g(16) x half(2) x dtile(8) = 6144 blocks.
__global__ __launch_bounds__(256) void cast_w0(const float* __restrict__ W0,
                                               f16* __restrict__ w0t){
  __shared__ float tile[64][33];
  int bid = blockIdx.x;
  int dt   = bid & 7;
  int half = (bid >> 3) & 1;
  int g    = (bid >> 4) & 15;
  int band = bid >> 8;
  int t = threadIdx.x;
  int c0 = half * 512 + g * 32;
  int d0 = dt * 64;
  int r  = t >> 2;            // 0..63 (d within tile)
  int cs = (t & 3) * 8;       // col chunk
  const float* src = W0 + ((size_t)(band * 512 + d0 + r)) * 1024 + c0 + cs;
  float4 v0 = *(const float4*)src;
  float4 v1 = *(const float4*)(src + 4);
  tile[r][cs + 0] = v0.x; tile[r][cs + 1] = v0.y; tile[r][cs + 2] = v0.z; tile[r][cs + 3] = v0.w;
  tile[r][cs + 4] = v1.x; tile[r][cs + 5] = v1.y; tile[r][cs + 6] = v1.z; tile[r][cs + 7] = v1.w;
  __syncthreads();
  int i   = t >> 3;           // 0..31 orig col within the 32-block
  int ds8 = (t & 7) * 8;      // d offset
  int prow = g * 64 + 2 * i + half;   // interleaved permuted row
  f16x8 o;
  #pragma unroll
  for (int k = 0; k < 8; ++k) o[k] = (f16)tile[ds8 + k][i];
  *(f16x8*)(w0t + ((size_t)(band * 1024 + prow)) * 512 + d0 + ds8) = o;
}

// W1 (512,4032) -> w1t (4032,512) f16, band-local interleave of (a,g) cols.
__global__ __launch_bounds__(256) void cast_w1(const float* __restrict__ W1,
                                               f16* __restrict__ w1t){
  int t = blockIdx.x * 256 + threadIdx.x;   // 258048 total
  int j  = t >> 6;
  int d8 = (t & 63) * 8;
  int band = 23;
  for (int b = 0; b < 24; ++b){ if (j < band_off2(b + 1)) { band = b; break; } }
  int off2 = band_off2(band);
  int di = band_di(band);
  int p = j - off2;
  int oc = off2 + ((p & 1) ? di + (p >> 1) : (p >> 1));
  f16x8 o;
  #pragma unroll
  for (int k = 0; k < 8; ++k) o[k] = (f16)W1[(size_t)(d8 + k) * 4032 + oc];
  *(f16x8*)(w1t + (size_t)j * 512 + d8) = o;
}

// biases, permuted to match interleaved columns (stay fp32)
__global__ __launch_bounds__(256) void cast_bias(const float* __restrict__ b0,
                                                 const float* __restrict__ b1,
                                                 float* __restrict__ b0p,
                                                 float* __restrict__ b1p){
  int t = blockIdx.x * 256 + threadIdx.x;
  if (t < NB * 1024){
    int p = t & 1023;
    int base = t & ~1023;
    b0p[t] = b0[base + ((p & 1) ? 512 + (p >> 1) : (p >> 1))];
  } else {
    int j = t - NB * 1024;
    if (j < 4032){
      int band = 23;
      for (int b = 0; b < 24; ++b){ if (j < band_off2(b + 1)) { band = b; break; } }
      int off2 = band_off2(band);
      int di = band_di(band);
      int p = j - off2;
      b1p[j] = b1[off2 + ((p & 1) ? di + (p >> 1) : (p >> 1))];
    }
  }
}

// ---------------- GEMM1: h = glu(x @ W0perm + b0perm), per band ----------------
// 128x128 tile, BK=64, 4 waves 2x2 (wave 64x64 = 4x4 16x16x32 frags).
// grid: band(24) x mt(16) x nt(8) = 3072 blocks.
__global__ __launch_bounds__(256) void gemm1(const f16* __restrict__ xh,
                                             const f16* __restrict__ w0t,
                                             const float* __restrict__ b0p,
                                             f16* __restrict__ h){
  __shared__ __align__(16) f16 As[128 * 64];
  __shared__ __align__(16) f16 Bs[128 * 64];
  int bid = blockIdx.x;
  int nt = bid & 7;
  int mt = (bid >> 3) & 15;
  int band = bid >> 7;
  int t = threadIdx.x;
  int lane = t & 63, w = t >> 6;
  int wm = w & 1, wn = w >> 1;
  int quad = lane >> 4, lc = lane & 15;
  floatx4 acc[4][4];
  #pragma unroll
  for (int i = 0; i < 4; ++i)
    #pragma unroll
    for (int j = 0; j < 4; ++j) acc[i][j] = floatx4{0.f, 0.f, 0.f, 0.f};

  const int mrow0 = mt * 128;
  const int nrow0 = nt * 128;
  for (int kb = 0; kb < 8; ++kb){
    const int k0 = kb * 64;
    #pragma unroll
    for (int p = 0; p < 4; ++p){          // A: 128 rows x 64 k
      int idx = p * 256 + t;
      int r = idx >> 3, s = idx & 7;
      int l = s ^ (r & 7);                // xor-swizzled chunk
      gl_lds16(xh + ((size_t)(mrow0 + r) * 24 + band) * 512 + k0 + l * 8,
               &As[idx * 8]);
    }
    #pragma unroll
    for (int p = 0; p < 4; ++p){          // B: 128 perm-cols x 64 k
      int idx = p * 256 + t;
      int r = idx >> 3, s = idx & 7;
      int l = s ^ (r & 7);
      gl_lds16(w0t + ((size_t)(band * 1024 + nrow0 + r)) * 512 + k0 + l * 8,
               &Bs[idx * 8]);
    }
    __syncthreads();
    #pragma unroll
    for (int s2 = 0; s2 < 2; ++s2){
      int kc = s2 * 4 + quad;
      f16x8 af[4], bf[4];
      #pragma unroll
      for (int i = 0; i < 4; ++i){
        int m = wm * 64 + i * 16 + lc;
        af[i] = *(const f16x8*)&As[m * 64 + ((kc ^ (m & 7)) << 3)];
        int n = wn * 64 + i * 16 + lc;
        bf[i] = *(const f16x8*)&Bs[n * 64 + ((kc ^ (n & 7)) << 3)];
      }
      #pragma unroll
      for (int i = 0; i < 4; ++i)
        #pragma unroll
        for (int j = 0; j < 4; ++j)
          acc[i][j] = __builtin_amdgcn_mfma_f32_16x16x32_f16(af[i], bf[j], acc[i][j], 0, 0, 0);
    }
    __syncthreads();
  }
  // epilogue: even perm-col = a, odd = gate (adjacent lane) -> shfl_xor(1)
  #pragma unroll
  for (int j = 0; j < 4; ++j){
    int colp = nrow0 + wn * 64 + j * 16 + lc;
    float bias = b0p[band * 1024 + colp];
    #pragma unroll
    for (int i = 0; i < 4; ++i){
      int mbase = mrow0 + wm * 64 + i * 16 + quad * 4;
      #pragma unroll
      for (int r = 0; r < 4; ++r){
        float z = acc[i][j][r] + bias;
        float zp = __shfl_xor(z, 1);
        if (!(lc & 1)){
          float hv = ftanh(z) * fsigm(zp);
          h[((size_t)band * BT + mbase + r) * 512 + (colp >> 1)] = (f16)hv;
        }
      }
    }
  }
}

// ---------------- GEMM2: out = glu(h_band @ W1perm + b1perm) ----------------
template<int BN>
__device__ __forceinline__ void gemm2_tile(const f16* __restrict__ hb,
                                           const f16* __restrict__ w1t,
                                           const float* __restrict__ b1p,
                                           float* __restrict__ out,
                                           int band, int mt, int ntile,
                                           f16* As, f16* Bs){
  constexpr int WNW = (BN == 128) ? 2 : 1;
  constexpr int WMW = 4 / WNW;
  constexpr int MF = 128 / (WMW * 16);
  constexpr int NF = BN / (WNW * 16);
  int t = threadIdx.x;
  int lane = t & 63, w = t >> 6;
  int wm = (WNW == 2) ? (w & 1) : w;
  int wn = (WNW == 2) ? (w >> 1) : 0;
  int quad = lane >> 4, lc = lane & 15;
  int off2 = band_off2(band);
  int jbase = off2 + ntile * BN;
  floatx4 acc[MF][NF];
  #pragma unroll
  for (int i = 0; i < MF; ++i)
    #pragma unroll
    for (int j = 0; j < NF; ++j) acc[i][j] = floatx4{0.f, 0.f, 0.f, 0.f};

  for (int kb = 0; kb < 8; ++kb){
    int k0 = kb * 64;
    #pragma unroll
    for (int p = 0; p < 4; ++p){          // A: 128 rows (contiguous h band)
      int idx = p * 256 + t;
      int r = idx >> 3, s = idx & 7, l = s ^ (r & 7);
      gl_lds16(hb + ((size_t)(mt * 128 + r)) * 512 + k0 + l * 8, &As[idx * 8]);
    }
    constexpr int BCH = BN * 8;
    constexpr int BP = (BCH + 255) / 256;
    #pragma unroll
    for (int p = 0; p < BP; ++p){         // B: BN rows
      int idx = p * 256 + t;
      if ((BCH % 256 == 0) || idx < BCH){
        int r = idx >> 3, s = idx & 7, l = s ^ (r & 7);
        gl_lds16(w1t + ((size_t)(jbase + r)) * 512 + k0 + l * 8, &Bs[idx * 8]);
      }
    }
    __syncthreads();
    #pragma unroll
    for (int s2 = 0; s2 < 2; ++s2){
      int kc = s2 * 4 + quad;
      f16x8 af[MF], bf[NF];
      #pragma unroll
      for (int i = 0; i < MF; ++i){
        int m = wm * (MF * 16) + i * 16 + lc;
        af[i] = *(const f16x8*)&As[m * 64 + ((kc ^ (m & 7)) << 3)];
      }
      #pragma unroll
      for (int j = 0; j < NF; ++j){
        int n = wn * (NF * 16) + j * 16 + lc;
        bf[j] = *(const f16x8*)&Bs[n * 64 + ((kc ^ (n & 7)) << 3)];
      }
      #pragma unroll
      for (int i = 0; i < MF; ++i)
        #pragma unroll
        for (int j = 0; j < NF; ++j)
          acc[i][j] = __builtin_amdgcn_mfma_f32_16x16x32_f16(af[i], bf[j], acc[i][j], 0, 0, 0);
    }
    __syncthreads();
  }
  int outbase = off2 >> 1;
  #pragma unroll
  for (int j = 0; j < NF; ++j){
    int p = ntile * BN + wn * (NF * 16) + j * 16 + lc;
    float bias = b1p[off2 + p];
    #pragma unroll
    for (int i = 0; i < MF; ++i){
      int mbase = mt * 128 + wm * (MF * 16) + i * 16 + quad * 4;
      #pragma unroll
      for (int r = 0; r < 4; ++r){
        float z = acc[i][j][r] + bias;
        float zp = __shfl_xor(z, 1);
        if (!(lc & 1)){
          out[(size_t)(mbase + r) * 2016 + outbase + (p >> 1)] = ftanh(z) * fsigm(zp);
        }
      }
    }
  }
}

// grid: 640 blocks.  bands 0-15: 16 blocks each (ntile=0); 16-19: 32; 20-23: 64.
__global__ __launch_bounds__(256) void gemm2(const f16* __restrict__ h,
                                             const f16* __restrict__ w1t,
                                             const float* __restrict__ b1p,
                                             float* __restrict__ out){
  __shared__ __align__(16) f16 As[128 * 64];
  __shared__ __align__(16) f16 Bs[128 * 64];
  int bid = blockIdx.x;
  int band, mt, ntile, cls;
  if (bid < 256){
    band = bid >> 4; mt = bid & 15; ntile = 0; cls = band >> 2;   // cls 0..3
  } else if (bid < 384){
    int rel = bid - 256; band = 16 + (rel >> 5);
    int r2 = rel & 31; mt = r2 & 15; ntile = r2 >> 4; cls = 4;
  } else {
    int rel = bid - 384; band = 20 + (rel >> 6);
    int r2 = rel & 63; mt = r2 & 15; ntile = r2 >> 4; cls = 5;
  }
  const f16* hb = h + ((size_t)band << 20);   // band * 2048 * 512
  switch (cls){
    case 0:  gemm2_tile<16 >(hb, w1t, b1p, out, band, mt, ntile, As, Bs); break;
    case 1:  gemm2_tile<32 >(hb, w1t, b1p, out, band, mt, ntile, As, Bs); break;
    case 2:  gemm2_tile<64 >(hb, w1t, b1p, out, band, mt, ntile, As, Bs); break;
    default: gemm2_tile<128>(hb, w1t, b1p, out, band, mt, ntile, As, Bs); break;
  }
}

// ---------------- launch ----------------
extern "C" void kernel_launch(void* const* d_in, const int* in_sizes, int n_in,
                              void* d_out, int out_size, void* d_ws, size_t ws_size,
                              hipStream_t stream){
  const float* x  = (const float*)d_in[0];
  const float* W0 = (const float*)d_in[1];
  const float* b0 = (const float*)d_in[2];
  const float* W1 = (const float*)d_in[3];
  const float* b1 = (const float*)d_in[4];
  char* ws = (char*)d_ws;
  // ws layout (total ~130.1 MB)
  f16*   xh   = (f16*)(ws);                       // 50,331,648 B
  f16*   hbuf = (f16*)(ws + 50331648);            // 50,331,648 B
  f16*   w0t  = (f16*)(ws + 100663296);           // 25,165,824 B
  f16*   w1t  = (f16*)(ws + 125829120);           //  4,128,768 B
  float* b0p  = (float*)(ws + 129957888);         //     98,304 B
  float* b1p  = (float*)(ws + 130056192);         //     16,128 B

  cast_x   <<<24576, 256, 0, stream>>>((const float4*)x, xh);
  cast_w0  <<<6144,  256, 0, stream>>>(W0, w0t);
  cast_w1  <<<1008,  256, 0, stream>>>(W1, w1t);
  cast_bias<<<112,   256, 0, stream>>>(b0, b1, b0p, b1p);
  gemm1    <<<3072,  256, 0, stream>>>(xh, w0t, b0p, hbuf);
  gemm2    <<<640,   256, 0, stream>>>(hbuf, w1t, b1p, (float*)d_out);
}

// Round 2
// 317.646 us; speedup vs baseline: 1.0748x; 1.0748x over previous
//
#include <hip/hip_runtime.h>
#include <cstdint>
#include <cstddef>

// MaskEstimator: 24 independent 2-layer GLU MLPs (fp16 MFMA path).
// R2 changes vs R1:
//  - gemm1/gemm2 K-loop: pre-computed staging pointers (+=128B/iter) and
//    hoisted LDS read addrs (s2=1 = s2=0 ^ 64B) -> cut K-loop VALU ~3x.
//  - gemm1 XCD-contiguous swizzle: each XCD gets a 3-band slice (fits L2).
//  - cast_w1 rewritten coalesced via LDS transpose tile.

typedef _Float16 f16;
typedef _Float16 f16x8 __attribute__((ext_vector_type(8)));
typedef float floatx4 __attribute__((ext_vector_type(4)));

#define BT 2048   // B*T
#define NB 24

__device__ __forceinline__ int band_di(int b){ return 8 << (b >> 2); }
__device__ __forceinline__ int band_off2(int b){
  int g = b >> 2;
  return 2 * (32 * ((1 << g) - 1) + (b & 3) * (8 << g));
}

__device__ __forceinline__ float fsigm(float x){
  return __builtin_amdgcn_rcpf(1.f + __expf(-x));
}
__device__ __forceinline__ float ftanh(float x){
  return 1.f - 2.f * __builtin_amdgcn_rcpf(1.f + __expf(2.f * x));
}

__device__ __forceinline__ void gl_lds16(const void* g, void* l){
  __builtin_amdgcn_global_load_lds(
      (const __attribute__((address_space(1))) unsigned int*)g,
      (__attribute__((address_space(3))) unsigned int*)l, 16, 0, 0);
}

// ---------------- cast kernels ----------------

__global__ __launch_bounds__(256) void cast_x(const float4* __restrict__ in,
                                              f16* __restrict__ out){
  int t = blockIdx.x * 256 + threadIdx.x;   // 6291456 total
  float4 v = in[t];
  typedef _Float16 f16x4 __attribute__((ext_vector_type(4)));
  f16x4 o = { (f16)v.x, (f16)v.y, (f16)v.z, (f16)v.w };
  *(f16x4*)(out + (size_t)t * 4) = o;
}

// W0 (24,512,1024) -> w0t (24,1024,512) f16, cols interleaved (a,g,a,g,...)
__global__ __launch_bounds__(256) void cast_w0(const float* __restrict__ W0,
                                               f16* __restrict__ w0t){
  __shared__ float tile[64][33];
  int bid = blockIdx.x;
  int dt   = bid & 7;
  int half = (bid >> 3) & 1;
  int g    = (bid >> 4) & 15;
  int band = bid >> 8;
  int t = threadIdx.x;
  int c0 = half * 512 + g * 32;
  int d0 = dt * 64;
  int r  = t >> 2;
  int cs = (t & 3) * 8;
  const float* src = W0 + ((size_t)(band * 512 + d0 + r)) * 1024 + c0 + cs;
  float4 v0 = *(const float4*)src;
  float4 v1 = *(const float4*)(src + 4);
  tile[r][cs + 0] = v0.x; tile[r][cs + 1] = v0.y; tile[r][cs + 2] = v0.z; tile[r][cs + 3] = v0.w;
  tile[r][cs + 4] = v1.x; tile[r][cs + 5] = v1.y; tile[r][cs + 6] = v1.z; tile[r][cs + 7] = v1.w;
  __syncthreads();
  int i   = t >> 3;
  int ds8 = (t & 7) * 8;
  int prow = g * 64 + 2 * i + half;
  f16x8 o;
  #pragma unroll
  for (int k = 0; k < 8; ++k) o[k] = (f16)tile[ds8 + k][i];
  *(f16x8*)(w0t + ((size_t)(band * 1024 + prow)) * 512 + d0 + ds8) = o;
}

// W1 (512,4032) -> w1t (4032,512) f16, band-local (a,g) interleave.
// Coalesced: 252 blocks, each handles 16 perm-cols x 512 d via LDS transpose.
// All band off2 are multiples of 16, so a 16-tile never crosses a band.
__global__ __launch_bounds__(256) void cast_w1(const float* __restrict__ W1,
                                               f16* __restrict__ w1t){
  __shared__ f16 tile[16][520];
  int jt = blockIdx.x;            // 0..251
  int j16 = jt * 16;
  int band = 23;
  for (int b = 0; b < 24; ++b){ if (j16 < band_off2(b + 1)) { band = b; break; } }
  int off2 = band_off2(band), di = band_di(band);
  int p0 = j16 - off2;            // multiple of 16
  int oca = off2 + (p0 >> 1);
  int ocg = oca + di;
  int t = threadIdx.x;
  #pragma unroll
  for (int hh = 0; hh < 2; ++hh){
    int d = hh * 256 + t;
    const float* rowp = W1 + (size_t)d * 4032;
    float4 a0 = *(const float4*)(rowp + oca);
    float4 a1 = *(const float4*)(rowp + oca + 4);
    float4 g0 = *(const float4*)(rowp + ocg);
    float4 g1 = *(const float4*)(rowp + ocg + 4);
    float av[8] = {a0.x,a0.y,a0.z,a0.w,a1.x,a1.y,a1.z,a1.w};
    float gv[8] = {g0.x,g0.y,g0.z,g0.w,g1.x,g1.y,g1.z,g1.w};
    #pragma unroll
    for (int q = 0; q < 8; ++q){
      tile[2*q][d]   = (f16)av[q];
      tile[2*q+1][d] = (f16)gv[q];
    }
  }
  __syncthreads();
  int j = t & 15, dc = (t >> 4) * 32;
  f16x8 o[4];
  #pragma unroll
  for (int k = 0; k < 4; ++k) o[k] = *(const f16x8*)&tile[j][dc + k*8];
  f16* dst = w1t + (size_t)(j16 + j) * 512 + dc;
  #pragma unroll
  for (int k = 0; k < 4; ++k) *(f16x8*)(dst + k*8) = o[k];
}

__global__ __launch_bounds__(256) void cast_bias(const float* __restrict__ b0,
                                                 const float* __restrict__ b1,
                                                 float* __restrict__ b0p,
                                                 float* __restrict__ b1p){
  int t = blockIdx.x * 256 + threadIdx.x;
  if (t < NB * 1024){
    int p = t & 1023;
    int base = t & ~1023;
    b0p[t] = b0[base + ((p & 1) ? 512 + (p >> 1) : (p >> 1))];
  } else {
    int j = t - NB * 1024;
    if (j < 4032){
      int band = 23;
      for (int b = 0; b < 24; ++b){ if (j < band_off2(b + 1)) { band = b; break; } }
      int off2 = band_off2(band);
      int di = band_di(band);
      int p = j - off2;
      b1p[j] = b1[off2 + ((p & 1) ? di + (p >> 1) : (p >> 1))];
    }
  }
}

// ---------------- GEMM1 ----------------
// 128x128 tile, BK=64, 4 waves 2x2. grid 3072, XCD-contiguous swizzle.
__global__ __launch_bounds__(256) void gemm1(const f16* __restrict__ xh,
                                             const f16* __restrict__ w0t,
                                             const float* __restrict__ b0p,
                                             f16* __restrict__ h){
  __shared__ __align__(16) f16 As[128 * 64];
  __shared__ __align__(16) f16 Bs[128 * 64];
  int bid = blockIdx.x;
  // XCD swizzle: xcd = bid & 7 (round-robin dispatch); give each XCD a
  // contiguous 384-work slice = 3 bands (x 2MB + w0 1MB per band < 4MB L2).
  int wid = (bid & 7) * 384 + (bid >> 3);
  int band = wid >> 7;
  int mt = (wid >> 3) & 15;
  int nt = wid & 7;
  int t = threadIdx.x;
  int lane = t & 63, w = t >> 6;
  int wm = w & 1, wn = w >> 1;
  int quad = lane >> 4, lc = lane & 15;
  const int mrow0 = mt * 128;
  const int nrow0 = nt * 128;

  // hoisted staging pointers (advance 128B = 64 f16 per K-iter)
  const char* gA[4]; const char* gB[4];
  f16* lA[4]; f16* lB[4];
  #pragma unroll
  for (int p = 0; p < 4; ++p){
    int idx = p * 256 + t;
    int r = idx >> 3, s = idx & 7, l = s ^ (r & 7);
    gA[p] = (const char*)(xh + ((size_t)(mrow0 + r) * 24 + band) * 512 + l * 8);
    gB[p] = (const char*)(w0t + ((size_t)(band * 1024 + nrow0 + r)) * 512 + l * 8);
    lA[p] = &As[idx * 8];
    lB[p] = &Bs[idx * 8];
  }
  // hoisted LDS read byte-offsets (s2=1 address = s2=0 ^ 64)
  int aoff[4], boff[4];
  #pragma unroll
  for (int i = 0; i < 4; ++i){
    int m = wm * 64 + i * 16 + lc;
    aoff[i] = (m * 64 + ((quad ^ (m & 7)) << 3)) * 2;
    int n = wn * 64 + i * 16 + lc;
    boff[i] = (n * 64 + ((quad ^ (n & 7)) << 3)) * 2;
  }
  const char* Ab = (const char*)As;
  const char* Bb = (const char*)Bs;

  floatx4 acc[4][4];
  #pragma unroll
  for (int i = 0; i < 4; ++i)
    #pragma unroll
    for (int j = 0; j < 4; ++j) acc[i][j] = floatx4{0.f, 0.f, 0.f, 0.f};

  for (int kb = 0; kb < 8; ++kb){
    #pragma unroll
    for (int p = 0; p < 4; ++p){ gl_lds16(gA[p], lA[p]); gA[p] += 128; }
    #pragma unroll
    for (int p = 0; p < 4; ++p){ gl_lds16(gB[p], lB[p]); gB[p] += 128; }
    __syncthreads();
    #pragma unroll
    for (int s2 = 0; s2 < 2; ++s2){
      f16x8 af[4], bf[4];
      #pragma unroll
      for (int i = 0; i < 4; ++i){
        af[i] = *(const f16x8*)(Ab + (aoff[i] ^ (s2 * 64)));
        bf[i] = *(const f16x8*)(Bb + (boff[i] ^ (s2 * 64)));
      }
      #pragma unroll
      for (int i = 0; i < 4; ++i)
        #pragma unroll
        for (int j = 0; j < 4; ++j)
          acc[i][j] = __builtin_amdgcn_mfma_f32_16x16x32_f16(af[i], bf[j], acc[i][j], 0, 0, 0);
    }
    __syncthreads();
  }
  #pragma unroll
  for (int j = 0; j < 4; ++j){
    int colp = nrow0 + wn * 64 + j * 16 + lc;
    float bias = b0p[band * 1024 + colp];
    #pragma unroll
    for (int i = 0; i < 4; ++i){
      int mbase = mrow0 + wm * 64 + i * 16 + quad * 4;
      #pragma unroll
      for (int r = 0; r < 4; ++r){
        float z = acc[i][j][r] + bias;
        float zp = __shfl_xor(z, 1);
        if (!(lc & 1)){
          float hv = ftanh(z) * fsigm(zp);
          h[((size_t)band * BT + mbase + r) * 512 + (colp >> 1)] = (f16)hv;
        }
      }
    }
  }
}

// ---------------- GEMM2 ----------------
template<int BN>
__device__ __forceinline__ void gemm2_tile(const f16* __restrict__ hb,
                                           const f16* __restrict__ w1t,
                                           const float* __restrict__ b1p,
                                           float* __restrict__ out,
                                           int band, int mt, int ntile,
                                           f16* As, f16* Bs){
  constexpr int WNW = (BN == 128) ? 2 : 1;
  constexpr int WMW = 4 / WNW;
  constexpr int MF = 128 / (WMW * 16);
  constexpr int NF = BN / (WNW * 16);
  int t = threadIdx.x;
  int lane = t & 63, w = t >> 6;
  int wm = (WNW == 2) ? (w & 1) : w;
  int wn = (WNW == 2) ? (w >> 1) : 0;
  int quad = lane >> 4, lc = lane & 15;
  int off2 = band_off2(band);
  int jbase = off2 + ntile * BN;

  constexpr int BCH = BN * 8;
  constexpr int BP = (BCH + 255) / 256;
  const char* gA[4]; const char* gB[BP];
  f16* lA[4]; f16* lB[BP];
  #pragma unroll
  for (int p = 0; p < 4; ++p){
    int idx = p * 256 + t;
    int r = idx >> 3, s = idx & 7, l = s ^ (r & 7);
    gA[p] = (const char*)(hb + ((size_t)(mt * 128 + r)) * 512 + l * 8);
    lA[p] = &As[idx * 8];
  }
  #pragma unroll
  for (int p = 0; p < BP; ++p){
    int idx = p * 256 + t;
    int r = idx >> 3, s = idx & 7, l = s ^ (r & 7);
    gB[p] = (const char*)(w1t + ((size_t)(jbase + r)) * 512 + l * 8);
    lB[p] = &Bs[idx * 8];
  }
  int aoff[MF], boff[NF];
  #pragma unroll
  for (int i = 0; i < MF; ++i){
    int m = wm * (MF * 16) + i * 16 + lc;
    aoff[i] = (m * 64 + ((quad ^ (m & 7)) << 3)) * 2;
  }
  #pragma unroll
  for (int j = 0; j < NF; ++j){
    int n = wn * (NF * 16) + j * 16 + lc;
    boff[j] = (n * 64 + ((quad ^ (n & 7)) << 3)) * 2;
  }
  const char* Ab = (const char*)As;
  const char* Bb = (const char*)Bs;

  floatx4 acc[MF][NF];
  #pragma unroll
  for (int i = 0; i < MF; ++i)
    #pragma unroll
    for (int j = 0; j < NF; ++j) acc[i][j] = floatx4{0.f, 0.f, 0.f, 0.f};

  for (int kb = 0; kb < 8; ++kb){
    #pragma unroll
    for (int p = 0; p < 4; ++p){ gl_lds16(gA[p], lA[p]); gA[p] += 128; }
    #pragma unroll
    for (int p = 0; p < BP; ++p){
      if ((BCH % 256 == 0) || (p * 256 + t) < BCH){
        gl_lds16(gB[p], lB[p]); gB[p] += 128;
      }
    }
    __syncthreads();
    #pragma unroll
    for (int s2 = 0; s2 < 2; ++s2){
      f16x8 af[MF], bf[NF];
      #pragma unroll
      for (int i = 0; i < MF; ++i)
        af[i] = *(const f16x8*)(Ab + (aoff[i] ^ (s2 * 64)));
      #pragma unroll
      for (int j = 0; j < NF; ++j)
        bf[j] = *(const f16x8*)(Bb + (boff[j] ^ (s2 * 64)));
      #pragma unroll
      for (int i = 0; i < MF; ++i)
        #pragma unroll
        for (int j = 0; j < NF; ++j)
          acc[i][j] = __builtin_amdgcn_mfma_f32_16x16x32_f16(af[i], bf[j], acc[i][j], 0, 0, 0);
    }
    __syncthreads();
  }
  int outbase = off2 >> 1;
  #pragma unroll
  for (int j = 0; j < NF; ++j){
    int p = ntile * BN + wn * (NF * 16) + j * 16 + lc;
    float bias = b1p[off2 + p];
    #pragma unroll
    for (int i = 0; i < MF; ++i){
      int mbase = mt * 128 + wm * (MF * 16) + i * 16 + quad * 4;
      #pragma unroll
      for (int r = 0; r < 4; ++r){
        float z = acc[i][j][r] + bias;
        float zp = __shfl_xor(z, 1);
        if (!(lc & 1)){
          out[(size_t)(mbase + r) * 2016 + outbase + (p >> 1)] = ftanh(z) * fsigm(zp);
        }
      }
    }
  }
}

__global__ __launch_bounds__(256) void gemm2(const f16* __restrict__ h,
                                             const f16* __restrict__ w1t,
                                             const float* __restrict__ b1p,
                                             float* __restrict__ out){
  __shared__ __align__(16) f16 As[128 * 64];
  __shared__ __align__(16) f16 Bs[128 * 64];
  int bid = blockIdx.x;
  int band, mt, ntile, cls;
  if (bid < 256){
    band = bid >> 4; mt = bid & 15; ntile = 0; cls = band >> 2;
  } else if (bid < 384){
    int rel = bid - 256; band = 16 + (rel >> 5);
    int r2 = rel & 31; mt = r2 & 15; ntile = r2 >> 4; cls = 4;
  } else {
    int rel = bid - 384; band = 20 + (rel >> 6);
    int r2 = rel & 63; mt = r2 & 15; ntile = r2 >> 4; cls = 5;
  }
  const f16* hb = h + ((size_t)band << 20);
  switch (cls){
    case 0:  gemm2_tile<16 >(hb, w1t, b1p, out, band, mt, ntile, As, Bs); break;
    case 1:  gemm2_tile<32 >(hb, w1t, b1p, out, band, mt, ntile, As, Bs); break;
    case 2:  gemm2_tile<64 >(hb, w1t, b1p, out, band, mt, ntile, As, Bs); break;
    default: gemm2_tile<128>(hb, w1t, b1p, out, band, mt, ntile, As, Bs); break;
  }
}

// ---------------- launch ----------------
extern "C" void kernel_launch(void* const* d_in, const int* in_sizes, int n_in,
                              void* d_out, int out_size, void* d_ws, size_t ws_size,
                              hipStream_t stream){
  const float* x  = (const float*)d_in[0];
  const float* W0 = (const float*)d_in[1];
  const float* b0 = (const float*)d_in[2];
  const float* W1 = (const float*)d_in[3];
  const float* b1 = (const float*)d_in[4];
  char* ws = (char*)d_ws;
  f16*   xh   = (f16*)(ws);                       // 50,331,648 B
  f16*   hbuf = (f16*)(ws + 50331648);            // 50,331,648 B
  f16*   w0t  = (f16*)(ws + 100663296);           // 25,165,824 B
  f16*   w1t  = (f16*)(ws + 125829120);           //  4,128,768 B
  float* b0p  = (float*)(ws + 129957888);         //     98,304 B
  float* b1p  = (float*)(ws + 130056192);         //     16,128 B

  cast_x   <<<24576, 256, 0, stream>>>((const float4*)x, xh);
  cast_w0  <<<6144,  256, 0, stream>>>(W0, w0t);
  cast_w1  <<<252,   256, 0, stream>>>(W1, w1t);
  cast_bias<<<112,   256, 0, stream>>>(b0, b1, b0p, b1p);
  gemm1    <<<3072,  256, 0, stream>>>(xh, w0t, b0p, hbuf);
  gemm2    <<<640,   256, 0, stream>>>(hbuf, w1t, b1p, (float*)d_out);
}